// Round 6
// baseline (738.104 us; speedup 1.0000x reference)
//
#include <hip/hip_runtime.h>
#include <math.h>

#define NGENES 978
#define EDIM   301
#define NNODES 10000
#define NEDGES 320000
#define KPAD   992      // 31*32 (K padded for MFMA)
#define NPAD   320      // 5*64  (N padded)
#define MPAD   10112    // 79*128 (M padded)
#define HP     320      // padded h row stride (floats)
#define ELLS   128      // ELL slots per node (P(deg>128) ~ 1e-40 for Poisson(32))

typedef float f4v __attribute__((ext_vector_type(4)));
typedef short s8v __attribute__((ext_vector_type(8)));

// ---------------- bf16 split: v ~= hi + lo (truncation split) ----------------
__device__ __forceinline__ void split_bf16(float v, short& hi, short& lo) {
    unsigned int b = __float_as_uint(v);
    hi = (short)(b >> 16);
    float hif = __uint_as_float(b & 0xFFFF0000u);
    float lof = v - hif;               // exact
    lo = (short)(__float_as_uint(lof) >> 16);
}

// ---------------- prep: zero cur + detect idx dtype ----------------
__global__ void prep_init(const unsigned int* __restrict__ ei, int* flag, int* cur) {
    int i = blockIdx.x * blockDim.x + threadIdx.x;
    if (i < NNODES) cur[i] = 0;
    if (blockIdx.x == 0 && threadIdx.x < 64) {
        // int64 edge_index (values < 2^31) => all odd 32-bit words zero
        unsigned int v = ei[2 * threadIdx.x + 1];
        unsigned long long nz = __ballot(v != 0u);
        if (threadIdx.x == 0) *flag = (nz == 0ULL) ? 1 : 0;
    }
}

__device__ __forceinline__ int load_idx(const void* ei, long long i, int is64) {
    return is64 ? (int)((const long long*)ei)[i] : ((const int*)ei)[i];
}

// ---------------- single-pass ELL build: ell[d][slot] = (src, w) ------------
__global__ void fill_ell(const void* __restrict__ ei, const float* __restrict__ w,
                         int* cur, int2* __restrict__ ell,
                         const int* __restrict__ flag) {
    int e = blockIdx.x * blockDim.x + threadIdx.x;
    if (e >= NEDGES) return;
    int is64 = *flag;
    int s = load_idx(ei, e, is64);
    int d = load_idx(ei, (long long)NEDGES + e, is64);
    int slot = atomicAdd(&cur[d], 1);
    if (slot < ELLS) ell[(size_t)d * ELLS + slot] = make_int2(s, __float_as_int(w[e]));
}

// ------- deg/dinv/selfc from ELL: wave per node (deg = 1 + sum w) -----------
__global__ __launch_bounds__(256) void deg_dinv(const int2* __restrict__ ell,
                                                const int* __restrict__ cur,
                                                float* __restrict__ dinv,
                                                float* __restrict__ selfc) {
    int n = (blockIdx.x * blockDim.x + threadIdx.x) >> 6;
    int lane = threadIdx.x & 63;
    if (n >= NNODES) return;
    int cnt = min(cur[n], ELLS);
    float s = 0.0f;
    for (int l = lane; l < cnt; l += 64)
        s += __int_as_float(ell[(size_t)n * ELLS + l].y);
    #pragma unroll
    for (int off = 32; off; off >>= 1) s += __shfl_xor(s, off);
    if (lane == 0) {
        float di = rsqrtf(1.0f + s);
        dinv[n] = di;
        selfc[n] = di * di;            // self-loop coefficient = 1/deg
    }
}

// ------- pre-scale: ell[n][l].w *= dinv[src]*dinv[n] (full GCN norm) --------
__global__ __launch_bounds__(256) void norm_ell(int2* __restrict__ ell,
                                                const int* __restrict__ cur,
                                                const float* __restrict__ dinv) {
    int n = (blockIdx.x * blockDim.x + threadIdx.x) >> 6;
    int lane = threadIdx.x & 63;
    if (n >= NNODES) return;
    int cnt = min(cur[n], ELLS);
    float dn = dinv[n];
    for (int l = lane; l < cnt; l += 64) {
        int2 p = ell[(size_t)n * ELLS + l];
        float coef = __int_as_float(p.y) * dinv[p.x] * dn;
        ell[(size_t)n * ELLS + l].y = __float_as_int(coef);
    }
}

// -------- convert x -> xh/xl [10000][992] and W -> W^T hi/lo [320][992] -----
#define XCH (NNODES * (KPAD / 8))     // 1,240,000 chunks of 8
#define WCH (NPAD * (KPAD / 8))       // 39,680
__global__ void cvt_xw(const float* __restrict__ x, const float* __restrict__ W,
                       short* __restrict__ xh, short* __restrict__ xl,
                       short* __restrict__ wh, short* __restrict__ wl) {
    int idx = blockIdx.x * blockDim.x + threadIdx.x;
    if (idx < XCH) {
        int r = idx / (KPAD / 8);
        int kc = (idx - r * (KPAD / 8)) * 8;
        s8v h8, l8;
        #pragma unroll
        for (int j = 0; j < 8; ++j) {
            int k = kc + j;
            float v = (k < NGENES) ? x[(size_t)r * NGENES + k] : 0.0f;
            short hi, lo;
            split_bf16(v, hi, lo);
            h8[j] = hi; l8[j] = lo;
        }
        *(s8v*)(xh + (size_t)r * KPAD + kc) = h8;
        *(s8v*)(xl + (size_t)r * KPAD + kc) = l8;
    } else if (idx < XCH + WCH) {
        int wi = idx - XCH;
        int n = wi / (KPAD / 8);
        int kc = (wi - n * (KPAD / 8)) * 8;
        s8v h8, l8;
        #pragma unroll
        for (int j = 0; j < 8; ++j) {
            int k = kc + j;
            float v = (n < EDIM && k < NGENES) ? W[(size_t)k * EDIM + n] : 0.0f;
            short hi, lo;
            split_bf16(v, hi, lo);
            h8[j] = hi; l8[j] = lo;
        }
        *(s8v*)(wh + (size_t)n * KPAD + kc) = h8;
        *(s8v*)(wl + (size_t)n * KPAD + kc) = l8;
    }
}

// ---------------- MFMA GEMM: h[N,320] = x @ W (bf16 3-pass split) -----------
// 128x64 block tile, 4 waves (2x2), wave tile 64x32, BK=32.
__global__ __launch_bounds__(256) void gemm_bf16(const short* __restrict__ xh,
                                                 const short* __restrict__ xl,
                                                 const short* __restrict__ wh,
                                                 const short* __restrict__ wl,
                                                 float* __restrict__ h) {
    __shared__ short Ah[128 * 40], Al[128 * 40], Bh[64 * 40], Bl[64 * 40];
    const int tid  = threadIdx.x;
    const int lane = tid & 63;
    const int w    = tid >> 6;
    const int wm   = (w >> 1) * 64;
    const int wn   = (w & 1) * 32;
    const int bm   = blockIdx.y * 128;
    const int bn   = blockIdx.x * 64;
    const int l15  = lane & 15;
    const int g8   = (lane >> 4) * 8;

    f4v acc[4][2] = {};

    const int arow0 = tid >> 2;
    const int aslot = (tid & 3) * 8;

    for (int ks = 0; ks < KPAD / 32; ++ks) {
        const int k0 = ks * 32;
        #pragma unroll
        for (int q = 0; q < 2; ++q) {
            const int row = q * 64 + arow0;
            const size_t goff = (size_t)(bm + row) * KPAD + k0 + aslot;
            s8v vh = *(const s8v*)(xh + goff);
            s8v vl = *(const s8v*)(xl + goff);
            *(s8v*)&Ah[row * 40 + aslot] = vh;
            *(s8v*)&Al[row * 40 + aslot] = vl;
        }
        {
            const int row = tid >> 2;
            const size_t goff = (size_t)(bn + row) * KPAD + k0 + aslot;
            s8v vh = *(const s8v*)(wh + goff);
            s8v vl = *(const s8v*)(wl + goff);
            *(s8v*)&Bh[row * 40 + aslot] = vh;
            *(s8v*)&Bl[row * 40 + aslot] = vl;
        }
        __syncthreads();
        s8v ah[4], al[4], bh[2], bl[2];
        #pragma unroll
        for (int fn = 0; fn < 2; ++fn) {
            const int r = wn + fn * 16 + l15;
            bh[fn] = *(const s8v*)&Bh[r * 40 + g8];
            bl[fn] = *(const s8v*)&Bl[r * 40 + g8];
        }
        #pragma unroll
        for (int fm = 0; fm < 4; ++fm) {
            const int r = wm + fm * 16 + l15;
            ah[fm] = *(const s8v*)&Ah[r * 40 + g8];
            al[fm] = *(const s8v*)&Al[r * 40 + g8];
        }
        #pragma unroll
        for (int fm = 0; fm < 4; ++fm)
            #pragma unroll
            for (int fn = 0; fn < 2; ++fn) {
                acc[fm][fn] = __builtin_amdgcn_mfma_f32_16x16x32_bf16(ah[fm], bh[fn], acc[fm][fn], 0, 0, 0);
                acc[fm][fn] = __builtin_amdgcn_mfma_f32_16x16x32_bf16(ah[fm], bl[fn], acc[fm][fn], 0, 0, 0);
                acc[fm][fn] = __builtin_amdgcn_mfma_f32_16x16x32_bf16(al[fm], bh[fn], acc[fm][fn], 0, 0, 0);
            }
        __syncthreads();
    }
    const int mrb = (lane >> 4) * 4;
    #pragma unroll
    for (int fm = 0; fm < 4; ++fm)
        #pragma unroll
        for (int fn = 0; fn < 2; ++fn) {
            const int col = bn + wn + fn * 16 + l15;
            #pragma unroll
            for (int r = 0; r < 4; ++r) {
                const int row = bm + wm + fm * 16 + mrb + r;
                if (row < NNODES) h[(size_t)row * HP + col] = acc[fm][fn][r];
            }
        }
}

// ------- fused gather + self-loop + bias + relu + coalesced broadcast -------
// One block (320 threads) per dst node; thread t owns column t. 8-edge ILP.
// Coefficients are pre-scaled (full dinv[s]*w*dinv[d]) -> pure fma loop.
__global__ __launch_bounds__(320) void gather_out(const float* __restrict__ h,
                                                  const float* __restrict__ selfc,
                                                  const float* __restrict__ bias,
                                                  const int2* __restrict__ ell,
                                                  const int* __restrict__ cur,
                                                  f4v* __restrict__ out) {
    __shared__ float row[HP];
    const int n = blockIdx.x;
    const int t = threadIdx.x;
    const int cnt = min(cur[n], ELLS);
    const int2* en = ell + (size_t)n * ELLS;

    float acc = 0.0f;
    int e = 0;
    for (; e + 8 <= cnt; e += 8) {
        int2 p[8];
        float v[8];
        #pragma unroll
        for (int j = 0; j < 8; ++j) p[j] = en[e + j];
        #pragma unroll
        for (int j = 0; j < 8; ++j) v[j] = h[(size_t)p[j].x * HP + t];
        #pragma unroll
        for (int j = 0; j < 8; ++j) acc = fmaf(__int_as_float(p[j].y), v[j], acc);
    }
    for (; e < cnt; ++e) {
        int2 p = en[e];
        acc = fmaf(__int_as_float(p.y), h[(size_t)p.x * HP + t], acc);
    }

    float v = acc + h[(size_t)n * HP + t] * selfc[n]
            + ((t < EDIM) ? bias[t] : 0.0f);
    row[t] = fmaxf(v, 0.0f);
    __syncthreads();

    // out[n][head][c][0..11] = 4 heads x 903 float4; coalesced, non-temporal
    f4v* o = out + (size_t)n * 4 * 903;
    #pragma unroll
    for (int q = 0; q < 3; ++q) {
        int p = q * 320 + t;
        if (p < 903) {
            const float vv = row[p / 3];
            f4v v4 = {vv, vv, vv, vv};
            __builtin_nontemporal_store(v4, &o[p]);
            __builtin_nontemporal_store(v4, &o[903 + p]);
            __builtin_nontemporal_store(v4, &o[1806 + p]);
            __builtin_nontemporal_store(v4, &o[2709 + p]);
        }
    }
}

// ---------------- launch ----------------
extern "C" void kernel_launch(void* const* d_in, const int* in_sizes, int n_in,
                              void* d_out, int out_size, void* d_ws, size_t ws_size,
                              hipStream_t stream) {
    const float* x  = (const float*)d_in[0];
    const void*  ei = d_in[1];
    const float* ew = (const float*)d_in[2];
    const float* W  = (const float*)d_in[3];
    const float* b  = (const float*)d_in[4];

    char* p = (char*)d_ws;
    int*   cur   = (int*)p;                  p += 40960;
    float* dinv  = (float*)p;                p += 40960;
    float* selfc = (float*)p;                p += 40960;
    int*   flag  = (int*)p;                  p += 256;
    int2*  ell   = (int2*)p;                 p += (size_t)NNODES * ELLS * 8;  // 10.24 MB
    float* h     = (float*)p;                p += (size_t)NNODES * HP * 4;    // 12.8 MB
    short* xh    = (short*)p;                p += (size_t)MPAD * KPAD * 2;
    short* xl    = (short*)p;                p += (size_t)MPAD * KPAD * 2;
    short* wh    = (short*)p;                p += (size_t)NPAD * KPAD * 2;
    short* wl    = (short*)p;                p += (size_t)NPAD * KPAD * 2;
    // total ~64 MB

    prep_init<<<40, 256, 0, stream>>>((const unsigned int*)ei, flag, cur);
    fill_ell<<<(NEDGES + 255) / 256, 256, 0, stream>>>(ei, ew, cur, ell, flag);
    deg_dinv<<<(NNODES * 64 + 255) / 256, 256, 0, stream>>>(ell, cur, dinv, selfc);
    norm_ell<<<(NNODES * 64 + 255) / 256, 256, 0, stream>>>(ell, cur, dinv);

    cvt_xw<<<(XCH + WCH + 255) / 256, 256, 0, stream>>>(x, W, xh, xl, wh, wl);

    dim3 ggrid(NPAD / 64, MPAD / 128);
    gemm_bf16<<<ggrid, 256, 0, stream>>>(xh, xl, wh, wl, h);

    gather_out<<<NNODES, 320, 0, stream>>>(h, selfc, b, ell, cur, (f4v*)d_out);
    (void)in_sizes; (void)n_in; (void)out_size; (void)ws_size;
}

// Round 7
// 731.779 us; speedup vs baseline: 1.0086x; 1.0086x over previous
//
#include <hip/hip_runtime.h>
#include <math.h>

#define NGENES 978
#define EDIM   301
#define NNODES 10000
#define NEDGES 320000
#define KPAD   992      // 31*32 (K padded for MFMA)
#define NPAD   320      // 5*64  (N padded)
#define MPAD   10112    // 79*128 (M padded)
#define HP     320      // padded h row stride (floats)
#define ELLS   128      // ELL slots per node (P(deg>128) ~ 1e-40 for Poisson(32))

typedef float    f4v __attribute__((ext_vector_type(4)));
typedef _Float16 h8v __attribute__((ext_vector_type(8)));

// ---------------- f16 split: v ~= hi + lo (hi RNE, lo exact-ish) -------------
// 2 x f16 mantissa (11+11 bits) ~ fp32 precision for our value range.
__device__ __forceinline__ void split_f16(float v, _Float16& hi, _Float16& lo) {
    hi = (_Float16)v;
    lo = (_Float16)(v - (float)hi);
}

// ---------------- prep: zero cur + detect idx dtype ----------------
__global__ void prep_init(const unsigned int* __restrict__ ei, int* flag, int* cur) {
    int i = blockIdx.x * blockDim.x + threadIdx.x;
    if (i < NNODES) cur[i] = 0;
    if (blockIdx.x == 0 && threadIdx.x < 64) {
        // int64 edge_index (values < 2^31) => all odd 32-bit words zero
        unsigned int v = ei[2 * threadIdx.x + 1];
        unsigned long long nz = __ballot(v != 0u);
        if (threadIdx.x == 0) *flag = (nz == 0ULL) ? 1 : 0;
    }
}

__device__ __forceinline__ int load_idx(const void* ei, long long i, int is64) {
    return is64 ? (int)((const long long*)ei)[i] : ((const int*)ei)[i];
}

// ---------------- single-pass ELL build: ell[d][slot] = (src, w) ------------
__global__ void fill_ell(const void* __restrict__ ei, const float* __restrict__ w,
                         int* cur, int2* __restrict__ ell,
                         const int* __restrict__ flag) {
    int e = blockIdx.x * blockDim.x + threadIdx.x;
    if (e >= NEDGES) return;
    int is64 = *flag;
    int s = load_idx(ei, e, is64);
    int d = load_idx(ei, (long long)NEDGES + e, is64);
    int slot = atomicAdd(&cur[d], 1);
    if (slot < ELLS) ell[(size_t)d * ELLS + slot] = make_int2(s, __float_as_int(w[e]));
}

// ------- deg/dinv from ELL: wave per node (deg = 1 + sum w) -----------------
__global__ __launch_bounds__(256) void deg_dinv(const int2* __restrict__ ell,
                                                const int* __restrict__ cur,
                                                float* __restrict__ dinv) {
    int n = (blockIdx.x * blockDim.x + threadIdx.x) >> 6;
    int lane = threadIdx.x & 63;
    if (n >= NNODES) return;
    int cnt = min(cur[n], ELLS);
    float s = 0.0f;
    for (int l = lane; l < cnt; l += 64)
        s += __int_as_float(ell[(size_t)n * ELLS + l].y);
    #pragma unroll
    for (int off = 32; off; off >>= 1) s += __shfl_xor(s, off);
    if (lane == 0) dinv[n] = rsqrtf(1.0f + s);
}

// -------- convert x -> xh/xl [10000][992] f16 and W -> W^T f16 [320][992] ---
#define XCH (NNODES * (KPAD / 8))     // 1,240,000 chunks of 8
#define WCH (NPAD * (KPAD / 8))       // 39,680
__global__ void cvt_xw(const float* __restrict__ x, const float* __restrict__ W,
                       _Float16* __restrict__ xh, _Float16* __restrict__ xl,
                       _Float16* __restrict__ wh) {
    int idx = blockIdx.x * blockDim.x + threadIdx.x;
    if (idx < XCH) {
        int r = idx / (KPAD / 8);
        int kc = (idx - r * (KPAD / 8)) * 8;
        h8v h8, l8;
        #pragma unroll
        for (int j = 0; j < 8; ++j) {
            int k = kc + j;
            float v = (k < NGENES) ? x[(size_t)r * NGENES + k] : 0.0f;
            _Float16 hi, lo;
            split_f16(v, hi, lo);
            h8[j] = hi; l8[j] = lo;
        }
        *(h8v*)(xh + (size_t)r * KPAD + kc) = h8;
        *(h8v*)(xl + (size_t)r * KPAD + kc) = l8;
    } else if (idx < XCH + WCH) {
        int wi = idx - XCH;
        int n = wi / (KPAD / 8);
        int kc = (wi - n * (KPAD / 8)) * 8;
        h8v h8;
        #pragma unroll
        for (int j = 0; j < 8; ++j) {
            int k = kc + j;
            float v = (n < EDIM && k < NGENES) ? W[(size_t)k * EDIM + n] : 0.0f;
            h8[j] = (_Float16)v;
        }
        *(h8v*)(wh + (size_t)n * KPAD + kc) = h8;
    }
}

// ---------------- MFMA GEMM: h[N,320] = x @ W (f16 2-pass split) ------------
// 128x64 block tile, 4 waves (2x2), wave tile 64x32, BK=32.
// LDS rows padded to 40 halfs (80 B) -> low bank aliasing on b128 reads.
__global__ __launch_bounds__(256) void gemm_f16(const _Float16* __restrict__ xh,
                                                const _Float16* __restrict__ xl,
                                                const _Float16* __restrict__ wh,
                                                float* __restrict__ h) {
    __shared__ _Float16 Ah[128 * 40], Al[128 * 40], Bh[64 * 40];
    const int tid  = threadIdx.x;
    const int lane = tid & 63;
    const int w    = tid >> 6;
    const int wm   = (w >> 1) * 64;
    const int wn   = (w & 1) * 32;
    const int bm   = blockIdx.y * 128;
    const int bn   = blockIdx.x * 64;
    const int l15  = lane & 15;
    const int g8   = (lane >> 4) * 8;

    f4v acc[4][2] = {};

    const int arow0 = tid >> 2;
    const int aslot = (tid & 3) * 8;

    for (int ks = 0; ks < KPAD / 32; ++ks) {
        const int k0 = ks * 32;
        #pragma unroll
        for (int q = 0; q < 2; ++q) {
            const int row = q * 64 + arow0;
            const size_t goff = (size_t)(bm + row) * KPAD + k0 + aslot;
            h8v vh = *(const h8v*)(xh + goff);
            h8v vl = *(const h8v*)(xl + goff);
            *(h8v*)&Ah[row * 40 + aslot] = vh;
            *(h8v*)&Al[row * 40 + aslot] = vl;
        }
        {
            const int row = tid >> 2;
            const size_t goff = (size_t)(bn + row) * KPAD + k0 + aslot;
            *(h8v*)&Bh[row * 40 + aslot] = *(const h8v*)(wh + goff);
        }
        __syncthreads();
        h8v ah[4], al[4], bh[2];
        #pragma unroll
        for (int fn = 0; fn < 2; ++fn) {
            const int r = wn + fn * 16 + l15;
            bh[fn] = *(const h8v*)&Bh[r * 40 + g8];
        }
        #pragma unroll
        for (int fm = 0; fm < 4; ++fm) {
            const int r = wm + fm * 16 + l15;
            ah[fm] = *(const h8v*)&Ah[r * 40 + g8];
            al[fm] = *(const h8v*)&Al[r * 40 + g8];
        }
        #pragma unroll
        for (int fm = 0; fm < 4; ++fm)
            #pragma unroll
            for (int fn = 0; fn < 2; ++fn) {
                acc[fm][fn] = __builtin_amdgcn_mfma_f32_16x16x32_f16(ah[fm], bh[fn], acc[fm][fn], 0, 0, 0);
                acc[fm][fn] = __builtin_amdgcn_mfma_f32_16x16x32_f16(al[fm], bh[fn], acc[fm][fn], 0, 0, 0);
            }
        __syncthreads();
    }
    // C write: D col = lane&15 (n), row = (lane>>4)*4 + reg (m)
    const int mrb = (lane >> 4) * 4;
    #pragma unroll
    for (int fm = 0; fm < 4; ++fm)
        #pragma unroll
        for (int fn = 0; fn < 2; ++fn) {
            const int col = bn + wn + fn * 16 + l15;
            #pragma unroll
            for (int r = 0; r < 4; ++r) {
                const int row = bm + wm + fm * 16 + mrb + r;
                if (row < NNODES) h[(size_t)row * HP + col] = acc[fm][fn][r];
            }
        }
}

// ------- fused gather + self-loop + bias + relu + coalesced broadcast -------
// One block (320 threads) per dst node; thread t owns column t. 8-edge ILP.
// coef = w*dinv[src] per edge; dinv[n] factored out of the whole sum.
__global__ __launch_bounds__(320) void gather_out(const float* __restrict__ h,
                                                  const float* __restrict__ dinv,
                                                  const float* __restrict__ bias,
                                                  const int2* __restrict__ ell,
                                                  const int* __restrict__ cur,
                                                  f4v* __restrict__ out) {
    __shared__ float row[HP];
    const int n = blockIdx.x;
    const int t = threadIdx.x;
    const int cnt = min(cur[n], ELLS);
    const int2* en = ell + (size_t)n * ELLS;

    float acc = 0.0f;
    int e = 0;
    for (; e + 8 <= cnt; e += 8) {
        int2 p[8];
        float v[8];
        #pragma unroll
        for (int j = 0; j < 8; ++j) p[j] = en[e + j];
        #pragma unroll
        for (int j = 0; j < 8; ++j) v[j] = h[(size_t)p[j].x * HP + t];
        #pragma unroll
        for (int j = 0; j < 8; ++j)
            acc = fmaf(__int_as_float(p[j].y) * dinv[p[j].x], v[j], acc);
    }
    for (; e < cnt; ++e) {
        int2 p = en[e];
        acc = fmaf(__int_as_float(p.y) * dinv[p.x], h[(size_t)p.x * HP + t], acc);
    }

    const float dn = dinv[n];
    float v = acc * dn + h[(size_t)n * HP + t] * (dn * dn)
            + ((t < EDIM) ? bias[t] : 0.0f);
    row[t] = fmaxf(v, 0.0f);
    __syncthreads();

    // out[n][head][c][0..11] = 4 heads x 903 float4; coalesced, non-temporal
    f4v* o = out + (size_t)n * 4 * 903;
    #pragma unroll
    for (int q = 0; q < 3; ++q) {
        int p = q * 320 + t;
        if (p < 903) {
            const float vv = row[p / 3];
            f4v v4 = {vv, vv, vv, vv};
            __builtin_nontemporal_store(v4, &o[p]);
            __builtin_nontemporal_store(v4, &o[903 + p]);
            __builtin_nontemporal_store(v4, &o[1806 + p]);
            __builtin_nontemporal_store(v4, &o[2709 + p]);
        }
    }
}

// ---------------- launch ----------------
extern "C" void kernel_launch(void* const* d_in, const int* in_sizes, int n_in,
                              void* d_out, int out_size, void* d_ws, size_t ws_size,
                              hipStream_t stream) {
    const float* x  = (const float*)d_in[0];
    const void*  ei = d_in[1];
    const float* ew = (const float*)d_in[2];
    const float* W  = (const float*)d_in[3];
    const float* b  = (const float*)d_in[4];

    char* p = (char*)d_ws;
    int*      cur  = (int*)p;                p += 40960;
    float*    dinv = (float*)p;              p += 40960;
    int*      flag = (int*)p;                p += 256;
    int2*     ell  = (int2*)p;               p += (size_t)NNODES * ELLS * 8;  // 10.24 MB
    float*    h    = (float*)p;              p += (size_t)NNODES * HP * 4;    // 12.8 MB
    _Float16* xh   = (_Float16*)p;           p += (size_t)MPAD * KPAD * 2;    // 20 MB
    _Float16* xl   = (_Float16*)p;           p += (size_t)MPAD * KPAD * 2;    // 20 MB
    _Float16* wh   = (_Float16*)p;           p += (size_t)NPAD * KPAD * 2;    // 0.64 MB
    // total ~64 MB

    prep_init<<<40, 256, 0, stream>>>((const unsigned int*)ei, flag, cur);
    fill_ell<<<(NEDGES + 255) / 256, 256, 0, stream>>>(ei, ew, cur, ell, flag);
    deg_dinv<<<(NNODES * 64 + 255) / 256, 256, 0, stream>>>(ell, cur, dinv);

    cvt_xw<<<(XCH + WCH + 255) / 256, 256, 0, stream>>>(x, W, xh, xl, wh);

    dim3 ggrid(NPAD / 64, MPAD / 128);
    gemm_f16<<<ggrid, 256, 0, stream>>>(xh, xl, wh, h);

    gather_out<<<NNODES, 320, 0, stream>>>(h, dinv, b, ell, cur, (f4v*)d_out);
    (void)in_sizes; (void)n_in; (void)out_size; (void)ws_size;
}